// Round 2
// baseline (302.523 us; speedup 1.0000x reference)
//
#include <hip/hip_runtime.h>

// Problem constants
#define S_DIM 8192
#define K_DIM 1024
#define RO_DIM 4096
#define O_DIM 64
#define SO (S_DIM * O_DIM)

typedef __attribute__((ext_vector_type(8))) __bf16 bf16x8;
typedef __attribute__((ext_vector_type(4))) float floatx4;
typedef __attribute__((ext_vector_type(4))) unsigned short ushx4;

__device__ inline unsigned short f2bf(float f) {
  unsigned u = __builtin_bit_cast(unsigned, f);
  u += 0x7fff + ((u >> 16) & 1);  // round-to-nearest-even
  return (unsigned short)(u >> 16);
}
__device__ inline float bf2f(unsigned short h) {
  unsigned u = ((unsigned)h) << 16;
  return __builtin_bit_cast(float, u);
}

// ---------------------------------------------------------------- cast X,W -> bf16
__global__ __launch_bounds__(256) void cast_kernel(const float* __restrict__ X,
                                                   const float* __restrict__ W,
                                                   unsigned short* __restrict__ Xb,
                                                   unsigned short* __restrict__ Wb) {
  int i = blockIdx.x * 256 + threadIdx.x;
  const int NX4 = (S_DIM * K_DIM) / 4;
  float4 v;
  unsigned short* dst;
  if (i < NX4) {
    v = ((const float4*)X)[i];
    dst = Xb + (size_t)i * 4;
  } else {
    int j = i - NX4;
    v = ((const float4*)W)[j];
    dst = Wb + (size_t)j * 4;
  }
  ushx4 o;
  o.x = f2bf(v.x); o.y = f2bf(v.y); o.z = f2bf(v.z); o.w = f2bf(v.w);
  *(ushx4*)dst = o;
}

// ---------------------------------------------------------------- fused GEMM+sigmoid+rule-reduce
// 128x128 tile, BK=32, 4 waves x (4x4) 16x16x32 MFMA fragments.
// LDS: tiles (16KB) UNIONed with epilogue ypart (32KB) -> 32KB block => 5 blocks/CU.
// K-chunk XOR swizzle ((row>>1)&3) applied at the GLOBAL address of
// global_load_lds, so LDS dest stays wave-uniform+lane*16; read side applies
// the same XOR -> 2-way max bank aliasing (free).
__global__ __launch_bounds__(256, 5) void gemm_kernel(const unsigned short* __restrict__ Xb,
                                                      const unsigned short* __restrict__ Wb,
                                                      const float* __restrict__ bias,
                                                      const float* __restrict__ lam,
                                                      unsigned short* __restrict__ partial) {
  __shared__ __align__(16) unsigned char smem[32768];
  unsigned short* Atile = (unsigned short*)smem;          // 128 rows x 32 k (8 KB)
  unsigned short* Btile = (unsigned short*)(smem + 8192); // 8 KB
  float* ypart = (float*)smem;                            // 128 x 64 fp32 (32 KB, epilogue only)

  const int t = threadIdx.x;
  const int lane = t & 63;
  const int w = t >> 6;
  const int wm = w & 1;        // wave row half (rows wm*64..+63)
  const int wn = w >> 1;       // wave col half (cols wn*64..+63) == rule within tile
  const int quad = lane >> 4;  // 0..3
  const int l16 = lane & 15;
  const int gm0 = blockIdx.y * 128;
  const int gn0 = blockIdx.x * 128;

  floatx4 acc[4][4];
#pragma unroll
  for (int mi = 0; mi < 4; ++mi)
#pragma unroll
    for (int ni = 0; ni < 4; ++ni) acc[mi][ni] = (floatx4){0.f, 0.f, 0.f, 0.f};

  for (int k0 = 0; k0 < K_DIM; k0 += 32) {
    __syncthreads();
#pragma unroll
    for (int i = 0; i < 2; ++i) {
      int idx = i * 256 + t;       // 0..511, lane-contiguous within each wave
      int row = idx >> 2;          // tile row 0..127
      int cc = idx & 3;           // LDS chunk slot within BK=32
      int gcc = cc ^ ((row >> 1) & 3);  // global k-chunk held in this slot
      const unsigned short* ga = Xb + (size_t)(gm0 + row) * K_DIM + k0 + gcc * 8;
      const unsigned short* gb = Wb + (size_t)(gn0 + row) * K_DIM + k0 + gcc * 8;
      __builtin_amdgcn_global_load_lds(
          (const __attribute__((address_space(1))) void*)ga,
          (__attribute__((address_space(3))) void*)(Atile + idx * 8), 16, 0, 0);
      __builtin_amdgcn_global_load_lds(
          (const __attribute__((address_space(1))) void*)gb,
          (__attribute__((address_space(3))) void*)(Btile + idx * 8), 16, 0, 0);
    }
    __syncthreads();

    bf16x8 af[4], bfr[4];
#pragma unroll
    for (int mi = 0; mi < 4; ++mi) {
      int row = wm * 64 + mi * 16 + l16;
      int cc = quad ^ ((row >> 1) & 3);
      af[mi] = *(const bf16x8*)(Atile + row * 32 + cc * 8);
    }
#pragma unroll
    for (int ni = 0; ni < 4; ++ni) {
      int row = wn * 64 + ni * 16 + l16;
      int cc = quad ^ ((row >> 1) & 3);
      bfr[ni] = *(const bf16x8*)(Btile + row * 32 + cc * 8);
    }
#pragma unroll
    for (int mi = 0; mi < 4; ++mi)
#pragma unroll
      for (int ni = 0; ni < 4; ++ni)
        acc[mi][ni] = __builtin_amdgcn_mfma_f32_16x16x32_bf16(af[mi], bfr[ni], acc[mi][ni], 0, 0, 0);
  }

  // ---- epilogue (tiles dead; smem reused as ypart) ----
  const int rule = blockIdx.x * 2 + wn;
  float bv[4];
#pragma unroll
  for (int ni = 0; ni < 4; ++ni) bv[ni] = bias[gn0 + wn * 64 + ni * 16 + l16];

  __syncthreads();
  if (wn == 0) {
#pragma unroll
    for (int mi = 0; mi < 4; ++mi) {
#pragma unroll
      for (int reg = 0; reg < 4; ++reg) {
        int row = wm * 64 + mi * 16 + quad * 4 + reg;
        float lv = lam[(size_t)(gm0 + row) * 64 + rule];
#pragma unroll
        for (int ni = 0; ni < 4; ++ni) {
          float z = acc[mi][ni][reg] + bv[ni];
          float h = 1.f / (1.f + __expf(-z));
          ypart[row * O_DIM + ni * 16 + l16] = lv * h;
        }
      }
    }
  }
  __syncthreads();
  if (wn == 1) {
#pragma unroll
    for (int mi = 0; mi < 4; ++mi) {
#pragma unroll
      for (int reg = 0; reg < 4; ++reg) {
        int row = wm * 64 + mi * 16 + quad * 4 + reg;
        float lv = lam[(size_t)(gm0 + row) * 64 + rule];
#pragma unroll
        for (int ni = 0; ni < 4; ++ni) {
          float z = acc[mi][ni][reg] + bv[ni];
          float h = 1.f / (1.f + __expf(-z));
          ypart[row * O_DIM + ni * 16 + l16] += lv * h;
        }
      }
    }
  }
  __syncthreads();

  // write 128x64 bf16 slice, coalesced (2048 x 8B by 256 threads)
  unsigned short* pdst = partial + (size_t)blockIdx.x * SO + (size_t)gm0 * O_DIM;
#pragma unroll
  for (int j = 0; j < 8; ++j) {
    int q = j * 256 + t;
    const float* src = ypart + q * 4;
    ushx4 o;
    o.x = f2bf(src[0]); o.y = f2bf(src[1]); o.z = f2bf(src[2]); o.w = f2bf(src[3]);
    ((ushx4*)pdst)[q] = o;
  }
}

// ---------------------------------------------------------------- final reduce over 32 N-tiles
__global__ __launch_bounds__(256) void reduce_kernel(const unsigned short* __restrict__ partial,
                                                     float* __restrict__ Y) {
  int i4 = blockIdx.x * 256 + threadIdx.x;  // index of a 4-elem group
  float s0 = 0.f, s1 = 0.f, s2 = 0.f, s3 = 0.f;
#pragma unroll
  for (int c = 0; c < 32; ++c) {
    ushx4 v = ((const ushx4*)(partial + (size_t)c * SO))[i4];
    s0 += bf2f(v.x); s1 += bf2f(v.y); s2 += bf2f(v.z); s3 += bf2f(v.w);
  }
  ((float4*)Y)[i4] = (float4){s0, s1, s2, s3};
}

extern "C" void kernel_launch(void* const* d_in, const int* in_sizes, int n_in,
                              void* d_out, int out_size, void* d_ws, size_t ws_size,
                              hipStream_t stream) {
  const float* X = (const float*)d_in[0];     // [8192,1024]
  const float* W = (const float*)d_in[1];     // [4096,1024]
  const float* b = (const float*)d_in[2];     // [4096]
  const float* lam = (const float*)d_in[3];   // [8192,64]
  float* Y = (float*)d_out;                   // [8192,64]

  unsigned short* Xb = (unsigned short*)d_ws;                       // 16 MB
  unsigned short* Wb = Xb + (size_t)S_DIM * K_DIM;                  // 8 MB
  unsigned short* partial = Wb + (size_t)RO_DIM * K_DIM;            // 32 slices x 1 MB = 32 MB

  int nCast = ((S_DIM + RO_DIM) * K_DIM / 4) / 256;  // 12288 blocks
  cast_kernel<<<nCast, 256, 0, stream>>>(X, W, Xb, Wb);

  dim3 g(RO_DIM / 128, S_DIM / 128);  // (32, 64)
  gemm_kernel<<<g, 256, 0, stream>>>(Xb, Wb, b, lam, partial);

  reduce_kernel<<<SO / 1024, 256, 0, stream>>>(partial, Y);
}

// Round 3
// 206.632 us; speedup vs baseline: 1.4641x; 1.4641x over previous
//
#include <hip/hip_runtime.h>

// Problem constants
#define S_DIM 8192
#define K_DIM 1024
#define RO_DIM 4096
#define O_DIM 64
#define SO (S_DIM * O_DIM)

typedef __attribute__((ext_vector_type(8))) __bf16 bf16x8;
typedef __attribute__((ext_vector_type(4))) float floatx4;
typedef __attribute__((ext_vector_type(4))) unsigned short ushx4;

__device__ inline unsigned short f2bf(float f) {
  unsigned u = __builtin_bit_cast(unsigned, f);
  u += 0x7fff + ((u >> 16) & 1);  // round-to-nearest-even
  return (unsigned short)(u >> 16);
}
__device__ inline float bf2f(unsigned short h) {
  unsigned u = ((unsigned)h) << 16;
  return __builtin_bit_cast(float, u);
}

// ---------------------------------------------------------------- cast X,W -> bf16
__global__ __launch_bounds__(256) void cast_kernel(const float* __restrict__ X,
                                                   const float* __restrict__ W,
                                                   unsigned short* __restrict__ Xb,
                                                   unsigned short* __restrict__ Wb) {
  int i = blockIdx.x * 256 + threadIdx.x;
  const int NX4 = (S_DIM * K_DIM) / 4;
  float4 v;
  unsigned short* dst;
  if (i < NX4) {
    v = ((const float4*)X)[i];
    dst = Xb + (size_t)i * 4;
  } else {
    int j = i - NX4;
    v = ((const float4*)W)[j];
    dst = Wb + (size_t)j * 4;
  }
  ushx4 o;
  o.x = f2bf(v.x); o.y = f2bf(v.y); o.z = f2bf(v.z); o.w = f2bf(v.w);
  *(ushx4*)dst = o;
}

// ---------------------------------------------------------------- fused GEMM+sigmoid+rule-reduce
// 128x128 tile, BK=32, 4 waves x (4x4) 16x16x32 MFMA fragments.
// LDS: tiles (16KB) UNIONed with epilogue ypart (32KB) -> 32KB block.
// NO min-waves launch bound: forcing 5 waves/EU made the allocator spill the
// 64-reg accumulator tile to scratch (R2: VGPR 92->48, WRITE_SIZE 65->417MB).
// At natural VGPR~92 the HW already fits 5 waves/SIMD; LDS allows 5 blocks/CU.
// K-chunk XOR swizzle ((row>>1)&3) applied at the GLOBAL address of
// global_load_lds (LDS dest stays wave-uniform+lane*16); read side applies
// the same XOR -> 2-way max bank aliasing (free). R2: conflicts 10M->1.6M.
__global__ __launch_bounds__(256) void gemm_kernel(const unsigned short* __restrict__ Xb,
                                                   const unsigned short* __restrict__ Wb,
                                                   const float* __restrict__ bias,
                                                   const float* __restrict__ lam,
                                                   unsigned short* __restrict__ partial) {
  __shared__ __align__(16) unsigned char smem[32768];
  unsigned short* Atile = (unsigned short*)smem;          // 128 rows x 32 k (8 KB)
  unsigned short* Btile = (unsigned short*)(smem + 8192); // 8 KB
  float* ypart = (float*)smem;                            // 128 x 64 fp32 (32 KB, epilogue only)

  const int t = threadIdx.x;
  const int lane = t & 63;
  const int w = t >> 6;
  const int wm = w & 1;        // wave row half (rows wm*64..+63)
  const int wn = w >> 1;       // wave col half (cols wn*64..+63) == rule within tile
  const int quad = lane >> 4;  // 0..3
  const int l16 = lane & 15;
  const int gm0 = blockIdx.y * 128;
  const int gn0 = blockIdx.x * 128;

  floatx4 acc[4][4];
#pragma unroll
  for (int mi = 0; mi < 4; ++mi)
#pragma unroll
    for (int ni = 0; ni < 4; ++ni) acc[mi][ni] = (floatx4){0.f, 0.f, 0.f, 0.f};

  for (int k0 = 0; k0 < K_DIM; k0 += 32) {
    __syncthreads();
#pragma unroll
    for (int i = 0; i < 2; ++i) {
      int idx = i * 256 + t;       // 0..511, lane-contiguous within each wave
      int row = idx >> 2;          // tile row 0..127
      int cc = idx & 3;            // LDS chunk slot within BK=32
      int gcc = cc ^ ((row >> 1) & 3);  // global k-chunk held in this slot
      const unsigned short* ga = Xb + (size_t)(gm0 + row) * K_DIM + k0 + gcc * 8;
      const unsigned short* gb = Wb + (size_t)(gn0 + row) * K_DIM + k0 + gcc * 8;
      __builtin_amdgcn_global_load_lds(
          (const __attribute__((address_space(1))) void*)ga,
          (__attribute__((address_space(3))) void*)(Atile + idx * 8), 16, 0, 0);
      __builtin_amdgcn_global_load_lds(
          (const __attribute__((address_space(1))) void*)gb,
          (__attribute__((address_space(3))) void*)(Btile + idx * 8), 16, 0, 0);
    }
    __syncthreads();

    bf16x8 af[4], bfr[4];
#pragma unroll
    for (int mi = 0; mi < 4; ++mi) {
      int row = wm * 64 + mi * 16 + l16;
      int cc = quad ^ ((row >> 1) & 3);
      af[mi] = *(const bf16x8*)(Atile + row * 32 + cc * 8);
    }
#pragma unroll
    for (int ni = 0; ni < 4; ++ni) {
      int row = wn * 64 + ni * 16 + l16;
      int cc = quad ^ ((row >> 1) & 3);
      bfr[ni] = *(const bf16x8*)(Btile + row * 32 + cc * 8);
    }
#pragma unroll
    for (int mi = 0; mi < 4; ++mi)
#pragma unroll
      for (int ni = 0; ni < 4; ++ni)
        acc[mi][ni] = __builtin_amdgcn_mfma_f32_16x16x32_bf16(af[mi], bfr[ni], acc[mi][ni], 0, 0, 0);
  }

  // ---- epilogue (tiles dead; smem reused as ypart) ----
  const int rule = blockIdx.x * 2 + wn;
  float bv[4];
#pragma unroll
  for (int ni = 0; ni < 4; ++ni) bv[ni] = bias[gn0 + wn * 64 + ni * 16 + l16];

  __syncthreads();
  if (wn == 0) {
#pragma unroll
    for (int mi = 0; mi < 4; ++mi) {
#pragma unroll
      for (int reg = 0; reg < 4; ++reg) {
        int row = wm * 64 + mi * 16 + quad * 4 + reg;
        float lv = lam[(size_t)(gm0 + row) * 64 + rule];
#pragma unroll
        for (int ni = 0; ni < 4; ++ni) {
          float z = acc[mi][ni][reg] + bv[ni];
          float h = 1.f / (1.f + __expf(-z));
          ypart[row * O_DIM + ni * 16 + l16] = lv * h;
        }
      }
    }
  }
  __syncthreads();
  if (wn == 1) {
#pragma unroll
    for (int mi = 0; mi < 4; ++mi) {
#pragma unroll
      for (int reg = 0; reg < 4; ++reg) {
        int row = wm * 64 + mi * 16 + quad * 4 + reg;
        float lv = lam[(size_t)(gm0 + row) * 64 + rule];
#pragma unroll
        for (int ni = 0; ni < 4; ++ni) {
          float z = acc[mi][ni][reg] + bv[ni];
          float h = 1.f / (1.f + __expf(-z));
          ypart[row * O_DIM + ni * 16 + l16] += lv * h;
        }
      }
    }
  }
  __syncthreads();

  // write 128x64 bf16 slice, coalesced (2048 x 8B by 256 threads)
  unsigned short* pdst = partial + (size_t)blockIdx.x * SO + (size_t)gm0 * O_DIM;
#pragma unroll
  for (int j = 0; j < 8; ++j) {
    int q = j * 256 + t;
    const float* src = ypart + q * 4;
    ushx4 o;
    o.x = f2bf(src[0]); o.y = f2bf(src[1]); o.z = f2bf(src[2]); o.w = f2bf(src[3]);
    ((ushx4*)pdst)[q] = o;
  }
}

// ---------------------------------------------------------------- final reduce over 32 N-tiles
__global__ __launch_bounds__(256) void reduce_kernel(const unsigned short* __restrict__ partial,
                                                     float* __restrict__ Y) {
  int i4 = blockIdx.x * 256 + threadIdx.x;  // index of a 4-elem group
  float s0 = 0.f, s1 = 0.f, s2 = 0.f, s3 = 0.f;
#pragma unroll
  for (int c = 0; c < 32; ++c) {
    ushx4 v = ((const ushx4*)(partial + (size_t)c * SO))[i4];
    s0 += bf2f(v.x); s1 += bf2f(v.y); s2 += bf2f(v.z); s3 += bf2f(v.w);
  }
  ((float4*)Y)[i4] = (float4){s0, s1, s2, s3};
}

extern "C" void kernel_launch(void* const* d_in, const int* in_sizes, int n_in,
                              void* d_out, int out_size, void* d_ws, size_t ws_size,
                              hipStream_t stream) {
  const float* X = (const float*)d_in[0];     // [8192,1024]
  const float* W = (const float*)d_in[1];     // [4096,1024]
  const float* b = (const float*)d_in[2];     // [4096]
  const float* lam = (const float*)d_in[3];   // [8192,64]
  float* Y = (float*)d_out;                   // [8192,64]

  unsigned short* Xb = (unsigned short*)d_ws;                       // 16 MB
  unsigned short* Wb = Xb + (size_t)S_DIM * K_DIM;                  // 8 MB
  unsigned short* partial = Wb + (size_t)RO_DIM * K_DIM;            // 32 slices x 1 MB = 32 MB

  int nCast = ((S_DIM + RO_DIM) * K_DIM / 4) / 256;  // 12288 blocks
  cast_kernel<<<nCast, 256, 0, stream>>>(X, W, Xb, Wb);

  dim3 g(RO_DIM / 128, S_DIM / 128);  // (32, 64)
  gemm_kernel<<<g, 256, 0, stream>>>(Xb, Wb, b, lam, partial);

  reduce_kernel<<<SO / 1024, 256, 0, stream>>>(partial, Y);
}